// Round 12
// baseline (613.166 us; speedup 1.0000x reference)
//
#include <hip/hip_runtime.h>
#include <hip/hip_bf16.h>
#include <cmath>

// ---------------------------------------------------------------------------
// StackAttCore: 3x LSTM + 2x additive attention. B=256 L=196 R=1024 A=512 E=1024
// Round 12: MEASUREMENT ROUND. R11 structure, but three probe dispatches are
// replicated (x4 gemmL0, x8 scores1, x4 smw1) so they exceed the ~115us fill
// kernels and surface in rocprof top-5 with counters. All replicas idempotent.
// ---------------------------------------------------------------------------

#define B_ 256
#define L_ 196
#define R_ 1024
#define A_ 512

typedef __attribute__((ext_vector_type(8))) short bf16x8;
typedef __attribute__((ext_vector_type(4))) float f32x4;

__device__ inline ushort f2bf(float f) {
  __hip_bfloat16 h = __float2bfloat16(f);
  return *(ushort*)&h;
}
__device__ inline uint pk2bf(float lo, float hi) {
  float2 t; t.x = lo; t.y = hi;
  __hip_bfloat162 h = __float22bfloat162_rn(t);
  return *(uint*)&h;
}
__device__ inline float ftanh(float x) {
  float e = __expf(2.f * x);
  return 1.f - 2.f / (e + 1.f);
}

struct GJob {
  float* C; int ldc; size_t pstride;
  const ushort* Xb; int ldx;
  const float* W1; int ldw1; int K1;
  const float* W2; int ldw2;
  int K, nbn, ns;
};

// shared GEMM body (tile 64x64, BK=64, 4 waves 2x2, swizzled LDS, dbuf)
__device__ void gemm_body(const GJob& j, int flat,
                          ushort (*lA)[4096], ushort (*lB)[4096])
{
  const int tid = threadIdx.x;
  const int n0 = (flat % j.nbn) * 64;
  const int r = flat / j.nbn;
  const int m0 = (r & 3) * 64;
  const int z = r >> 2;
  const int Ks = j.K / j.ns;
  const int k0 = z * Ks;
  float* C = j.C + (size_t)z * j.pstride;

  const int srow = tid >> 2;
  const int sq = tid & 3;
  const int wz0 = srow * 64 + (((sq * 2) ^ (srow & 7)) * 8);
  const int wz1 = srow * 64 + (((sq * 2 + 1) ^ (srow & 7)) * 8);

  const int lane = tid & 63;
  const int wid = tid >> 6;
  const int wr = wid >> 1, wc = wid & 1;
  const int l15 = lane & 15, l4 = lane >> 4;
  int aoff[2][2], boff[2][2];
#pragma unroll
  for (int m = 0; m < 2; m++)
#pragma unroll
    for (int s = 0; s < 2; s++) {
      int ra = wr * 32 + m * 16 + l15;
      int rb = wc * 32 + m * 16 + l15;
      int sl = s * 4 + l4;
      aoff[m][s] = ra * 64 + ((sl ^ (ra & 7)) * 8);
      boff[m][s] = rb * 64 + ((sl ^ (rb & 7)) * 8);
    }

  f32x4 zero = {0.f, 0.f, 0.f, 0.f};
  f32x4 acc[2][2];
  acc[0][0] = zero; acc[0][1] = zero; acc[1][0] = zero; acc[1][1] = zero;

  uint4 ax0, ax1;
  f32x4 bw[4];
  const int NT = Ks >> 6;
  const ushort* aB = j.Xb + (size_t)(m0 + srow) * j.ldx + sq * 16;

  auto g_load = [&](int kt) {
    const int kk = k0 + kt * 64;
    ax0 = *(const uint4*)(aB + kk);
    ax1 = *(const uint4*)(aB + kk + 8);
    const float* wp = (kk < j.K1)
        ? j.W1 + (size_t)(n0 + srow) * j.ldw1 + kk + sq * 16
        : j.W2 + (size_t)(n0 + srow) * j.ldw2 + (kk - j.K1) + sq * 16;
    bw[0] = *(const f32x4*)wp;
    bw[1] = *(const f32x4*)(wp + 4);
    bw[2] = *(const f32x4*)(wp + 8);
    bw[3] = *(const f32x4*)(wp + 12);
  };
  auto s_write = [&](int buf) {
    *(uint4*)&lA[buf][wz0] = ax0;
    *(uint4*)&lA[buf][wz1] = ax1;
    uint4 b0, b1;
    b0.x = pk2bf(bw[0].x, bw[0].y); b0.y = pk2bf(bw[0].z, bw[0].w);
    b0.z = pk2bf(bw[1].x, bw[1].y); b0.w = pk2bf(bw[1].z, bw[1].w);
    b1.x = pk2bf(bw[2].x, bw[2].y); b1.y = pk2bf(bw[2].z, bw[2].w);
    b1.z = pk2bf(bw[3].x, bw[3].y); b1.w = pk2bf(bw[3].z, bw[3].w);
    *(uint4*)&lB[buf][wz0] = b0;
    *(uint4*)&lB[buf][wz1] = b1;
  };
  auto compute = [&](int buf) {
#pragma unroll
    for (int s = 0; s < 2; s++) {
      bf16x8 af0 = *(const bf16x8*)&lA[buf][aoff[0][s]];
      bf16x8 af1 = *(const bf16x8*)&lA[buf][aoff[1][s]];
      bf16x8 bf0 = *(const bf16x8*)&lB[buf][boff[0][s]];
      bf16x8 bf1 = *(const bf16x8*)&lB[buf][boff[1][s]];
      acc[0][0] = __builtin_amdgcn_mfma_f32_16x16x32_bf16(af0, bf0, acc[0][0], 0, 0, 0);
      acc[0][1] = __builtin_amdgcn_mfma_f32_16x16x32_bf16(af0, bf1, acc[0][1], 0, 0, 0);
      acc[1][0] = __builtin_amdgcn_mfma_f32_16x16x32_bf16(af1, bf0, acc[1][0], 0, 0, 0);
      acc[1][1] = __builtin_amdgcn_mfma_f32_16x16x32_bf16(af1, bf1, acc[1][1], 0, 0, 0);
    }
  };

  g_load(0);
  s_write(0);
  __syncthreads();
  int cur = 0;
  for (int kt = 0; kt < NT; kt++) {
    if (kt + 1 < NT) g_load(kt + 1);
    compute(cur);
    if (kt + 1 < NT) s_write(cur ^ 1);
    __syncthreads();
    cur ^= 1;
  }

#pragma unroll
  for (int m = 0; m < 2; m++)
#pragma unroll
    for (int n = 0; n < 2; n++) {
      const int col = n0 + wc * 32 + n * 16 + l15;
#pragma unroll
      for (int j2 = 0; j2 < 4; j2++) {
        const int row = m0 + wr * 32 + m * 16 + l4 * 4 + j2;
        C[(size_t)row * j.ldc + col] = acc[m][n][j2];
      }
    }
}

__global__ __launch_bounds__(256) void gemm_k(GJob ja, GJob jb, int totalA)
{
  __shared__ ushort lA[2][64 * 64];
  __shared__ ushort lB[2][64 * 64];
  const bool isA = ((int)blockIdx.x < totalA);
  gemm_body(isA ? ja : jb, isA ? blockIdx.x : blockIdx.x - totalA, lA, lB);
}

// PROBE: grid = rep * total; flat = blockIdx % total (idempotent re-writes)
__global__ __launch_bounds__(256) void gemm_probe(GJob j, int total)
{
  __shared__ ushort lA[2][64 * 64];
  __shared__ ushort lB[2][64 * 64];
  gemm_body(j, (int)blockIdx.x % total, lA, lB);
}

__global__ __launch_bounds__(256) void pack5(
    const float* __restrict__ s0, ushort* __restrict__ d0,
    const float* __restrict__ s1, ushort* __restrict__ d1,
    const float* __restrict__ s2, ushort* __restrict__ d2,
    const float* __restrict__ s3, ushort* __restrict__ d3,
    const float* __restrict__ s4, ushort* __restrict__ d4)
{
  const int seg = blockIdx.x >> 8;
  const int row = blockIdx.x & 255;
  const int col = threadIdx.x * 4;
  const float* s;
  ushort* d;
  switch (seg) {
    case 0: s = s0; d = d0; break;
    case 1: s = s1; d = d1; break;
    case 2: s = s2; d = d2; break;
    case 3: s = s3; d = d3; break;
    default: s = s4; d = d4; break;
  }
  float4 v = *(const float4*)(s + (size_t)row * 1024 + col);
  uint2 o;
  o.x = pk2bf(v.x, v.y);
  o.y = pk2bf(v.z, v.w);
  *(uint2*)(d + (size_t)row * 3072 + col) = o;
}

__global__ __launch_bounds__(256) void lstm_gates(
    const float* __restrict__ Sp, int ns,
    const float* __restrict__ bi, const float* __restrict__ bh,
    const float* __restrict__ c_prev,
    float* __restrict__ h_out, float* __restrict__ c_out,
    ushort* __restrict__ hb16,
    float* __restrict__ h_out2,
    const float* __restrict__ q2p, int q2ns,
    const float* __restrict__ eb, ushort* __restrict__ q2b)
{
  const int idx = blockIdx.x * 256 + threadIdx.x;
  const int b = idx >> 8;
  const int c4 = (idx & 255) * 4;
  const size_t base = (size_t)b * 5120 + c4;

  f32x4 g[5];
#pragma unroll
  for (int j = 0; j < 5; j++) g[j] = (f32x4){0.f, 0.f, 0.f, 0.f};
  for (int s = 0; s < ns; s++) {
    const float* sp = Sp + (size_t)s * 1310720 + base;
#pragma unroll
    for (int j = 0; j < 5; j++) g[j] += *(const f32x4*)(sp + j * 1024);
  }
#pragma unroll
  for (int j = 0; j < 5; j++) {
    g[j] += *(const f32x4*)(bi + j * 1024 + c4);
    g[j] += *(const f32x4*)(bh + j * 1024 + c4);
  }

  const int oidx = b * 1024 + c4;
  f32x4 cp = *(const f32x4*)(c_prev + oidx);
  f32x4 hv, cv;
#pragma unroll
  for (int i = 0; i < 4; i++) {
    float ig = 1.f / (1.f + __expf(-g[0][i]));
    float fg = 1.f / (1.f + __expf(-g[1][i]));
    float og = 1.f / (1.f + __expf(-g[2][i]));
    float it = fmaxf(g[3][i], g[4][i]);
    float c  = fg * cp[i] + ig * it;
    cv[i] = c;
    hv[i] = og * ftanh(c);
  }
  *(f32x4*)(h_out + oidx) = hv;
  *(f32x4*)(c_out + oidx) = cv;
  if (hb16) {
    uint2 o;
    o.x = pk2bf(hv[0], hv[1]);
    o.y = pk2bf(hv[2], hv[3]);
    *(uint2*)(hb16 + (size_t)b * 3072 + c4) = o;
  }
  if (h_out2) *(f32x4*)(h_out2 + oidx) = hv;
  if (q2p) {
    f32x4 a = hv;
    for (int s = 0; s < q2ns; s++)
      a += *(const f32x4*)(q2p + (size_t)s * 262144 + oidx);
    a += *(const f32x4*)(eb + c4);
    uint2 o;
    o.x = pk2bf(a[0], a[1]);
    o.y = pk2bf(a[2], a[3]);
    *(uint2*)(q2b + oidx) = o;
  }
}

__device__ void scores_body(float* scores, const float* p_att,
                            const float* attHp, int ns, const float* hb,
                            const float* aw, const float* ab, int wid)
{
  int lane = threadIdx.x & 63;
  int b = wid / L_;
  int l = wid % L_;
  const float* p = p_att + ((size_t)b * L_ + l) * A_;
  f32x4 q0 = {0.f, 0.f, 0.f, 0.f}, q1 = q0;
  for (int s = 0; s < ns; s++) {
    const float* qp = attHp + (size_t)s * 131072 + (size_t)b * A_ + lane * 8;
    q0 += *(const f32x4*)qp;
    q1 += *(const f32x4*)(qp + 4);
  }
  f32x4 p0 = *(const f32x4*)(p + lane * 8);
  f32x4 p1 = *(const f32x4*)(p + lane * 8 + 4);
  f32x4 h0 = *(const f32x4*)(hb + lane * 8);
  f32x4 h1 = *(const f32x4*)(hb + lane * 8 + 4);
  f32x4 w0 = *(const f32x4*)(aw + lane * 8);
  f32x4 w1 = *(const f32x4*)(aw + lane * 8 + 4);
  float part = 0.f;
#pragma unroll
  for (int i = 0; i < 4; i++) part += ftanh(p0[i] + q0[i] + h0[i]) * w0[i];
#pragma unroll
  for (int i = 0; i < 4; i++) part += ftanh(p1[i] + q1[i] + h1[i]) * w1[i];
#pragma unroll
  for (int off = 32; off > 0; off >>= 1) part += __shfl_down(part, off);
  if (lane == 0) scores[wid] = part + ab[0];
}

__global__ __launch_bounds__(256) void att_scores(
    float* __restrict__ scores, const float* __restrict__ p_att,
    const float* __restrict__ attHp, int ns, const float* __restrict__ hb,
    const float* __restrict__ aw, const float* __restrict__ ab)
{
  int wid = blockIdx.x * 4 + (threadIdx.x >> 6);
  if (wid >= B_ * L_) return;
  scores_body(scores, p_att, attHp, ns, hb, aw, ab, wid);
}

// PROBE: grid = rep * 12544
__global__ __launch_bounds__(256) void att_scores_probe(
    float* __restrict__ scores, const float* __restrict__ p_att,
    const float* __restrict__ attHp, int ns, const float* __restrict__ hb,
    const float* __restrict__ aw, const float* __restrict__ ab)
{
  int wid = ((int)blockIdx.x % 12544) * 4 + (threadIdx.x >> 6);
  if (wid >= B_ * L_) return;
  scores_body(scores, p_att, attHp, ns, hb, aw, ab, wid);
}

__device__ void smw_body(ushort* dst, const float* sc, const float* feats,
                         int vb, float* red, float* wbuf, f32x4* part)
{
  const int b = vb >> 2;
  const int dc = vb & 3;
  const int t = threadIdx.x;
  const int q = t & 63;
  const int ph = t >> 6;

  float v = (t < L_) ? sc[b * L_ + t] : -1e30f;
  red[t] = v;
  __syncthreads();
  for (int s = 128; s > 0; s >>= 1) {
    if (t < s) red[t] = fmaxf(red[t], red[t + s]);
    __syncthreads();
  }
  float m = red[0];
  __syncthreads();
  float e = (t < L_) ? __expf(v - m) : 0.f;
  red[t] = e;
  __syncthreads();
  for (int s = 128; s > 0; s >>= 1) {
    if (t < s) red[t] += red[t + s];
    __syncthreads();
  }
  if (t < L_) wbuf[t] = e * (1.f / red[0]);
  __syncthreads();

  const int col = dc * 256 + q * 4;
  const float* f = feats + (size_t)b * L_ * R_ + col;
  f32x4 acc = {0.f, 0.f, 0.f, 0.f};
#pragma unroll 7
  for (int l = ph; l < L_; l += 4) {
    acc += wbuf[l] * *(const f32x4*)(f + (size_t)l * R_);
  }
  if (ph != 0) part[(ph - 1) * 64 + q] = acc;
  __syncthreads();
  if (ph == 0) {
    acc += part[q];
    acc += part[64 + q];
    acc += part[128 + q];
    uint2 o;
    o.x = pk2bf(acc[0], acc[1]);
    o.y = pk2bf(acc[2], acc[3]);
    *(uint2*)(dst + (size_t)b * 3072 + col) = o;
  }
}

__global__ __launch_bounds__(256) void att_smw(
    ushort* __restrict__ dst, const float* __restrict__ sc,
    const float* __restrict__ feats)
{
  __shared__ float red[256];
  __shared__ float wbuf[208];
  __shared__ f32x4 part[192];
  smw_body(dst, sc, feats, blockIdx.x, red, wbuf, part);
}

// PROBE: grid = rep * 1024
__global__ __launch_bounds__(256) void att_smw_probe(
    ushort* __restrict__ dst, const float* __restrict__ sc,
    const float* __restrict__ feats)
{
  __shared__ float red[256];
  __shared__ float wbuf[208];
  __shared__ f32x4 part[192];
  smw_body(dst, sc, feats, (int)blockIdx.x % 1024, red, wbuf, part);
}

extern "C" void kernel_launch(void* const* d_in, const int* in_sizes, int n_in,
                              void* d_out, int out_size, void* d_ws, size_t ws_size,
                              hipStream_t stream)
{
  const float* xt        = (const float*)d_in[0];
  const float* fc        = (const float*)d_in[1];
  const float* att_feats = (const float*)d_in[2];
  const float* p_att     = (const float*)d_in[3];
  const float* st_h      = (const float*)d_in[4];
  const float* st_c      = (const float*)d_in[5];
  const float* wi[3] = {(const float*)d_in[6],  (const float*)d_in[10], (const float*)d_in[14]};
  const float* bi[3] = {(const float*)d_in[7],  (const float*)d_in[11], (const float*)d_in[15]};
  const float* wh[3] = {(const float*)d_in[8],  (const float*)d_in[12], (const float*)d_in[16]};
  const float* bh[3] = {(const float*)d_in[9],  (const float*)d_in[13], (const float*)d_in[17]};
  const float* a_hw[2] = {(const float*)d_in[18], (const float*)d_in[22]};
  const float* a_hb[2] = {(const float*)d_in[19], (const float*)d_in[23]};
  const float* a_aw[2] = {(const float*)d_in[20], (const float*)d_in[24]};
  const float* a_ab[2] = {(const float*)d_in[21], (const float*)d_in[25]};
  const float* emb2_w = (const float*)d_in[26];
  const float* emb2_b = (const float*)d_in[27];

  float* out    = (float*)d_out;
  float* out_h2 = out;
  float* out_h  = out + 262144;
  float* out_c  = out + 262144 + 786432;
  const int BR = B_ * R_;
  const int ns = 4;

  dim3 blk(256);
  auto jobL = [&](float* C, const ushort* Xb, const float* W1, const float* W2) {
    GJob j;
    j.C = C; j.ldc = 5120; j.pstride = (size_t)256 * 5120;
    j.Xb = Xb; j.ldx = 3072;
    j.W1 = W1; j.ldw1 = 2048; j.K1 = 2048;
    j.W2 = W2; j.ldw2 = 1024;
    j.K = 3072; j.nbn = 80; j.ns = ns;
    return j;
  };
  auto jobS = [&](float* C, int ldc, const ushort* Xb, int ldx,
                  const float* W, int ldw, int K, int N) {
    GJob j;
    j.C = C; j.ldc = ldc; j.pstride = (size_t)256 * ldc;
    j.Xb = Xb; j.ldx = ldx;
    j.W1 = W; j.ldw1 = ldw; j.K1 = K;
    j.W2 = W; j.ldw2 = ldw;
    j.K = K; j.nbn = N / 64; j.ns = ns;
    return j;
  };
  auto launch1 = [&](GJob j) {
    int total = j.nbn * 4 * j.ns;
    hipLaunchKernelGGL(gemm_k, dim3(total), blk, 0, stream, j, j, total);
  };
  auto launch2 = [&](GJob a, GJob b) {
    int ta = a.nbn * 4 * a.ns;
    int tb = b.nbn * 4 * b.ns;
    hipLaunchKernelGGL(gemm_k, dim3(ta + tb), blk, 0, stream, a, b, ta);
  };

  const size_t NEED = 32706560u;
  float*  Sp    = (float*)d_ws;
  ushort* Xb0   = (ushort*)(Sp + (size_t)ns * 1310720);
  ushort* Xb1   = Xb0 + 786432;
  ushort* Xb2   = Xb1 + 786432;
  float*  attHp = (float*)(Xb2 + 786432);
  float*  sc    = attHp + (size_t)ns * 131072;

  if (ws_size >= NEED) {
    float*  q2p = sc + 50176;
    ushort* q2b = (ushort*)(q2p + (size_t)4 * 262144);

    pack5<<<1280, 256, 0, stream>>>(xt, Xb0, fc, Xb0 + 1024, st_h, Xb0 + 2048,
                                    st_h + BR, Xb1 + 2048,
                                    st_h + 2 * BR, Xb2 + 2048);

    // ---- LSTM 0 : PROBE x4 (idempotent replicas; counters visible in top-5)
    {
      GJob j = jobL(Sp, Xb0, wi[0], wh[0]);
      int total = j.nbn * 4 * j.ns;   // 1280
      hipLaunchKernelGGL(gemm_probe, dim3(4 * total), blk, 0, stream, j, total);
    }
    lstm_gates<<<256, 256, 0, stream>>>(Sp, ns, bi[0], bh[0], st_c,
                                        out_h, out_c, Xb1, nullptr,
                                        nullptr, 0, nullptr, nullptr);

    // ---- Attention 1 : scores PROBE x8, smw PROBE x4
    launch1(jobS(attHp, 512, Xb1, 3072, a_hw[0], 1024, 1024, 512));
    att_scores_probe<<<8 * 12544, 256, 0, stream>>>(sc, p_att, attHp, ns,
                                                    a_hb[0], a_aw[0], a_ab[0]);
    att_smw_probe<<<4 * 1024, 256, 0, stream>>>(Xb1 + 1024, sc, att_feats);

    // ---- LSTM1 GEMM || q2 GEMM
    launch2(jobL(Sp, Xb1, wi[1], wh[1]),
            jobS(q2p, 1024, Xb1 + 1024, 3072, emb2_w, 1024, 1024, 1024));
    lstm_gates<<<256, 256, 0, stream>>>(Sp, ns, bi[1], bh[1], st_c + BR,
                                        out_h + BR, out_c + BR, Xb2, nullptr,
                                        q2p, 4, emb2_b, q2b);

    // ---- Attention 2
    launch1(jobS(attHp, 512, q2b, 1024, a_hw[1], 1024, 1024, 512));
    att_scores<<<(B_ * L_) / 4, 256, 0, stream>>>(sc, p_att, attHp, ns,
                                                  a_hb[1], a_aw[1], a_ab[1]);
    att_smw<<<B_ * 4, 256, 0, stream>>>(Xb2 + 1024, sc, att_feats);

    // ---- LSTM 2
    launch1(jobL(Sp, Xb2, wi[2], wh[2]));
    lstm_gates<<<256, 256, 0, stream>>>(Sp, ns, bi[2], bh[2], st_c + 2 * BR,
                                        out_h + 2 * BR, out_c + 2 * BR,
                                        nullptr, out_h2,
                                        nullptr, 0, nullptr, nullptr);
    return;
  }

  // fallback (no probes)
  float*  q2p = Sp;
  ushort* q2b = (ushort*)(Sp + (size_t)ns * 262144);

  pack5<<<1280, 256, 0, stream>>>(xt, Xb0, fc, Xb0 + 1024, st_h, Xb0 + 2048,
                                  st_h + BR, Xb1 + 2048,
                                  st_h + 2 * BR, Xb2 + 2048);
  launch1(jobL(Sp, Xb0, wi[0], wh[0]));
  lstm_gates<<<256, 256, 0, stream>>>(Sp, ns, bi[0], bh[0], st_c,
                                      out_h, out_c, Xb1, nullptr,
                                      nullptr, 0, nullptr, nullptr);
  launch1(jobS(attHp, 512, Xb1, 3072, a_hw[0], 1024, 1024, 512));
  att_scores<<<(B_ * L_) / 4, 256, 0, stream>>>(sc, p_att, attHp, ns,
                                                a_hb[0], a_aw[0], a_ab[0]);
  att_smw<<<B_ * 4, 256, 0, stream>>>(Xb1 + 1024, sc, att_feats);
  launch1(jobL(Sp, Xb1, wi[1], wh[1]));
  lstm_gates<<<256, 256, 0, stream>>>(Sp, ns, bi[1], bh[1], st_c + BR,
                                      out_h + BR, out_c + BR, Xb2, nullptr,
                                      nullptr, 0, nullptr, nullptr);
  launch1(jobS(q2p, 1024, Xb1 + 1024, 3072, emb2_w, 1024, 1024, 1024));
  lstm_gates<<<256, 256, 0, stream>>>(Sp, ns, bi[1], bh[1], st_c + BR,
                                      out_h + BR, out_c + BR, Xb2, nullptr,
                                      q2p, 4, emb2_b, q2b);
  launch1(jobS(attHp, 512, q2b, 1024, a_hw[1], 1024, 1024, 512));
  att_scores<<<(B_ * L_) / 4, 256, 0, stream>>>(sc, p_att, attHp, ns,
                                                a_hb[1], a_aw[1], a_ab[1]);
  att_smw<<<B_ * 4, 256, 0, stream>>>(Xb2 + 1024, sc, att_feats);
  launch1(jobL(Sp, Xb2, wi[2], wh[2]));
  lstm_gates<<<256, 256, 0, stream>>>(Sp, ns, bi[2], bh[2], st_c + 2 * BR,
                                      out_h + 2 * BR, out_c + 2 * BR,
                                      nullptr, out_h2,
                                      nullptr, 0, nullptr, nullptr);
}

// Round 13
// 272.831 us; speedup vs baseline: 2.2474x; 2.2474x over previous
//
#include <hip/hip_runtime.h>
#include <hip/hip_bf16.h>
#include <cmath>

// ---------------------------------------------------------------------------
// StackAttCore: 3x LSTM + 2x additive attention. B=256 L=196 R=1024 A=512 E=1024
// Round 13: R11 structure + (1) raw v_exp/v_rcp builtins replacing IEEE div /
// libm exp (R12 probe: scores VALU-bound at 76% from div sequences),
// (2) att_prep kernel precomputing qsum = sum(attHp slices) + hb.
// ---------------------------------------------------------------------------

#define B_ 256
#define L_ 196
#define R_ 1024
#define A_ 512

typedef __attribute__((ext_vector_type(8))) short bf16x8;
typedef __attribute__((ext_vector_type(4))) float f32x4;

__device__ inline ushort f2bf(float f) {
  __hip_bfloat16 h = __float2bfloat16(f);
  return *(ushort*)&h;
}
__device__ inline uint pk2bf(float lo, float hi) {
  float2 t; t.x = lo; t.y = hi;
  __hip_bfloat162 h = __float22bfloat162_rn(t);
  return *(uint*)&h;
}
// fast transcendentals: single v_exp_f32 / v_rcp_f32 (1 ULP; threshold 0.105)
__device__ inline float fexp2(float x) { return __builtin_amdgcn_exp2f(x); }
__device__ inline float frcp(float x)  { return __builtin_amdgcn_rcpf(x); }
__device__ inline float ftanh(float x) {
  float e = fexp2(x * 2.8853900817779268f);       // e^(2x)
  return 1.f - 2.f * frcp(e + 1.f);
}
__device__ inline float fsigm(float x) {
  return frcp(1.f + fexp2(-1.4426950408889634f * x));
}

struct GJob {
  float* C; int ldc; size_t pstride;
  const ushort* Xb; int ldx;
  const float* W1; int ldw1; int K1;
  const float* W2; int ldw2;
  int K, nbn, ns;
};

// Tile 64x64, BK=64, 4 waves (2x2), 16x16x32 MFMA, XOR-swizzled LDS, dbuf.
__global__ __launch_bounds__(256) void gemm_k(GJob ja, GJob jb, int totalA)
{
  const bool isA = ((int)blockIdx.x < totalA);
  GJob j = isA ? ja : jb;
  const int flat = isA ? blockIdx.x : blockIdx.x - totalA;

  __shared__ ushort lA[2][64 * 64];
  __shared__ ushort lB[2][64 * 64];
  const int tid = threadIdx.x;

  const int n0 = (flat % j.nbn) * 64;
  const int r = flat / j.nbn;
  const int m0 = (r & 3) * 64;
  const int z = r >> 2;
  const int Ks = j.K / j.ns;
  const int k0 = z * Ks;
  float* C = j.C + (size_t)z * j.pstride;

  const int srow = tid >> 2;
  const int sq = tid & 3;
  const int wz0 = srow * 64 + (((sq * 2) ^ (srow & 7)) * 8);
  const int wz1 = srow * 64 + (((sq * 2 + 1) ^ (srow & 7)) * 8);

  const int lane = tid & 63;
  const int wid = tid >> 6;
  const int wr = wid >> 1, wc = wid & 1;
  const int l15 = lane & 15, l4 = lane >> 4;
  int aoff[2][2], boff[2][2];
#pragma unroll
  for (int m = 0; m < 2; m++)
#pragma unroll
    for (int s = 0; s < 2; s++) {
      int ra = wr * 32 + m * 16 + l15;
      int rb = wc * 32 + m * 16 + l15;
      int sl = s * 4 + l4;
      aoff[m][s] = ra * 64 + ((sl ^ (ra & 7)) * 8);
      boff[m][s] = rb * 64 + ((sl ^ (rb & 7)) * 8);
    }

  f32x4 zero = {0.f, 0.f, 0.f, 0.f};
  f32x4 acc[2][2];
  acc[0][0] = zero; acc[0][1] = zero; acc[1][0] = zero; acc[1][1] = zero;

  uint4 ax0, ax1;
  f32x4 bw[4];
  const int NT = Ks >> 6;
  const ushort* aB = j.Xb + (size_t)(m0 + srow) * j.ldx + sq * 16;

  auto g_load = [&](int kt) {
    const int kk = k0 + kt * 64;
    ax0 = *(const uint4*)(aB + kk);
    ax1 = *(const uint4*)(aB + kk + 8);
    const float* wp = (kk < j.K1)
        ? j.W1 + (size_t)(n0 + srow) * j.ldw1 + kk + sq * 16
        : j.W2 + (size_t)(n0 + srow) * j.ldw2 + (kk - j.K1) + sq * 16;
    bw[0] = *(const f32x4*)wp;
    bw[1] = *(const f32x4*)(wp + 4);
    bw[2] = *(const f32x4*)(wp + 8);
    bw[3] = *(const f32x4*)(wp + 12);
  };
  auto s_write = [&](int buf) {
    *(uint4*)&lA[buf][wz0] = ax0;
    *(uint4*)&lA[buf][wz1] = ax1;
    uint4 b0, b1;
    b0.x = pk2bf(bw[0].x, bw[0].y); b0.y = pk2bf(bw[0].z, bw[0].w);
    b0.z = pk2bf(bw[1].x, bw[1].y); b0.w = pk2bf(bw[1].z, bw[1].w);
    b1.x = pk2bf(bw[2].x, bw[2].y); b1.y = pk2bf(bw[2].z, bw[2].w);
    b1.z = pk2bf(bw[3].x, bw[3].y); b1.w = pk2bf(bw[3].z, bw[3].w);
    *(uint4*)&lB[buf][wz0] = b0;
    *(uint4*)&lB[buf][wz1] = b1;
  };
  auto compute = [&](int buf) {
#pragma unroll
    for (int s = 0; s < 2; s++) {
      bf16x8 af0 = *(const bf16x8*)&lA[buf][aoff[0][s]];
      bf16x8 af1 = *(const bf16x8*)&lA[buf][aoff[1][s]];
      bf16x8 bf0 = *(const bf16x8*)&lB[buf][boff[0][s]];
      bf16x8 bf1 = *(const bf16x8*)&lB[buf][boff[1][s]];
      acc[0][0] = __builtin_amdgcn_mfma_f32_16x16x32_bf16(af0, bf0, acc[0][0], 0, 0, 0);
      acc[0][1] = __builtin_amdgcn_mfma_f32_16x16x32_bf16(af0, bf1, acc[0][1], 0, 0, 0);
      acc[1][0] = __builtin_amdgcn_mfma_f32_16x16x32_bf16(af1, bf0, acc[1][0], 0, 0, 0);
      acc[1][1] = __builtin_amdgcn_mfma_f32_16x16x32_bf16(af1, bf1, acc[1][1], 0, 0, 0);
    }
  };

  g_load(0);
  s_write(0);
  __syncthreads();
  int cur = 0;
  for (int kt = 0; kt < NT; kt++) {
    if (kt + 1 < NT) g_load(kt + 1);
    compute(cur);
    if (kt + 1 < NT) s_write(cur ^ 1);
    __syncthreads();
    cur ^= 1;
  }

#pragma unroll
  for (int m = 0; m < 2; m++)
#pragma unroll
    for (int n = 0; n < 2; n++) {
      const int col = n0 + wc * 32 + n * 16 + l15;
#pragma unroll
      for (int j2 = 0; j2 < 4; j2++) {
        const int row = m0 + wr * 32 + m * 16 + l4 * 4 + j2;
        C[(size_t)row * j.ldc + col] = acc[m][n][j2];
      }
    }
}

__global__ __launch_bounds__(256) void pack5(
    const float* __restrict__ s0, ushort* __restrict__ d0,
    const float* __restrict__ s1, ushort* __restrict__ d1,
    const float* __restrict__ s2, ushort* __restrict__ d2,
    const float* __restrict__ s3, ushort* __restrict__ d3,
    const float* __restrict__ s4, ushort* __restrict__ d4)
{
  const int seg = blockIdx.x >> 8;
  const int row = blockIdx.x & 255;
  const int col = threadIdx.x * 4;
  const float* s;
  ushort* d;
  switch (seg) {
    case 0: s = s0; d = d0; break;
    case 1: s = s1; d = d1; break;
    case 2: s = s2; d = d2; break;
    case 3: s = s3; d = d3; break;
    default: s = s4; d = d4; break;
  }
  float4 v = *(const float4*)(s + (size_t)row * 1024 + col);
  uint2 o;
  o.x = pk2bf(v.x, v.y);
  o.y = pk2bf(v.z, v.w);
  *(uint2*)(d + (size_t)row * 3072 + col) = o;
}

// gates: sum ns partials, biases, activations -> h, c (+ optional fused q2b)
__global__ __launch_bounds__(256) void lstm_gates(
    const float* __restrict__ Sp, int ns,
    const float* __restrict__ bi, const float* __restrict__ bh,
    const float* __restrict__ c_prev,
    float* __restrict__ h_out, float* __restrict__ c_out,
    ushort* __restrict__ hb16,
    float* __restrict__ h_out2,
    const float* __restrict__ q2p, int q2ns,
    const float* __restrict__ eb, ushort* __restrict__ q2b)
{
  const int idx = blockIdx.x * 256 + threadIdx.x;
  const int b = idx >> 8;
  const int c4 = (idx & 255) * 4;
  const size_t base = (size_t)b * 5120 + c4;

  f32x4 g[5];
#pragma unroll
  for (int j = 0; j < 5; j++) g[j] = (f32x4){0.f, 0.f, 0.f, 0.f};
  for (int s = 0; s < ns; s++) {
    const float* sp = Sp + (size_t)s * 1310720 + base;
#pragma unroll
    for (int j = 0; j < 5; j++) g[j] += *(const f32x4*)(sp + j * 1024);
  }
#pragma unroll
  for (int j = 0; j < 5; j++) {
    g[j] += *(const f32x4*)(bi + j * 1024 + c4);
    g[j] += *(const f32x4*)(bh + j * 1024 + c4);
  }

  const int oidx = b * 1024 + c4;
  f32x4 cp = *(const f32x4*)(c_prev + oidx);
  f32x4 hv, cv;
#pragma unroll
  for (int i = 0; i < 4; i++) {
    float ig = fsigm(g[0][i]);
    float fg = fsigm(g[1][i]);
    float og = fsigm(g[2][i]);
    float it = fmaxf(g[3][i], g[4][i]);
    float c  = fg * cp[i] + ig * it;
    cv[i] = c;
    hv[i] = og * ftanh(c);
  }
  *(f32x4*)(h_out + oidx) = hv;
  *(f32x4*)(c_out + oidx) = cv;
  if (hb16) {
    uint2 o;
    o.x = pk2bf(hv[0], hv[1]);
    o.y = pk2bf(hv[2], hv[3]);
    *(uint2*)(hb16 + (size_t)b * 3072 + c4) = o;
  }
  if (h_out2) *(f32x4*)(h_out2 + oidx) = hv;
  if (q2p) {
    f32x4 a = hv;
    for (int s = 0; s < q2ns; s++)
      a += *(const f32x4*)(q2p + (size_t)s * 262144 + oidx);
    a += *(const f32x4*)(eb + c4);
    uint2 o;
    o.x = pk2bf(a[0], a[1]);
    o.y = pk2bf(a[2], a[3]);
    *(uint2*)(q2b + oidx) = o;
  }
}

// qsum[b,a] = sum_s attHp[s][b][a] + hb[a]   (131072 floats, 128 blocks)
__global__ __launch_bounds__(256) void att_prep(
    float* __restrict__ qsum, const float* __restrict__ attHp, int ns,
    const float* __restrict__ hb)
{
  const int i4 = (blockIdx.x * 256 + threadIdx.x) * 4;
  f32x4 a = *(const f32x4*)(hb + (i4 & (A_ - 1)));
  for (int s = 0; s < ns; s++)
    a += *(const f32x4*)(attHp + (size_t)s * 131072 + i4);
  *(f32x4*)(qsum + i4) = a;
}

// scores[b,l] = sum_a tanh(p + qsum[b,a]) * aw[a] + ab ; wave per (b,l)
__global__ __launch_bounds__(256) void att_scores(
    float* __restrict__ scores,
    const float* __restrict__ p_att,
    const float* __restrict__ qsum,
    const float* __restrict__ aw,
    const float* __restrict__ ab)
{
  int wid = blockIdx.x * 4 + (threadIdx.x >> 6);
  if (wid >= B_ * L_) return;
  int lane = threadIdx.x & 63;
  int b = wid / L_;
  int l = wid % L_;
  const float* p = p_att + ((size_t)b * L_ + l) * A_ + lane * 8;
  const float* q = qsum + (size_t)b * A_ + lane * 8;

  f32x4 q0 = *(const f32x4*)q;
  f32x4 q1 = *(const f32x4*)(q + 4);
  f32x4 p0 = *(const f32x4*)p;
  f32x4 p1 = *(const f32x4*)(p + 4);
  f32x4 w0 = *(const f32x4*)(aw + lane * 8);
  f32x4 w1 = *(const f32x4*)(aw + lane * 8 + 4);
  float part = 0.f;
#pragma unroll
  for (int i = 0; i < 4; i++) part += ftanh(p0[i] + q0[i]) * w0[i];
#pragma unroll
  for (int i = 0; i < 4; i++) part += ftanh(p1[i] + q1[i]) * w1[i];
#pragma unroll
  for (int off = 32; off > 0; off >>= 1) part += __shfl_down(part, off);
  if (lane == 0) scores[wid] = part + ab[0];
}

// fused softmax(196) + weighted sum over att_feats -> bf16 (stride 3072)
__global__ __launch_bounds__(256) void att_smw(
    ushort* __restrict__ dst,
    const float* __restrict__ sc,
    const float* __restrict__ feats)
{
  const int b = blockIdx.x >> 2;
  const int dc = blockIdx.x & 3;
  const int t = threadIdx.x;
  const int q = t & 63;
  const int ph = t >> 6;
  __shared__ float red[256];
  __shared__ float wbuf[208];
  __shared__ f32x4 part[3][64];

  float v = (t < L_) ? sc[b * L_ + t] : -1e30f;
  red[t] = v;
  __syncthreads();
  for (int s = 128; s > 0; s >>= 1) {
    if (t < s) red[t] = fmaxf(red[t], red[t + s]);
    __syncthreads();
  }
  float m = red[0];
  __syncthreads();
  float e = (t < L_) ? fexp2((v - m) * 1.4426950408889634f) : 0.f;
  red[t] = e;
  __syncthreads();
  for (int s = 128; s > 0; s >>= 1) {
    if (t < s) red[t] += red[t + s];
    __syncthreads();
  }
  if (t < L_) wbuf[t] = e * frcp(red[0]);
  __syncthreads();

  const int col = dc * 256 + q * 4;
  const float* f = feats + (size_t)b * L_ * R_ + col;
  f32x4 acc = {0.f, 0.f, 0.f, 0.f};
#pragma unroll 7
  for (int l = ph; l < L_; l += 4) {
    acc += wbuf[l] * *(const f32x4*)(f + (size_t)l * R_);
  }
  if (ph != 0) part[ph - 1][q] = acc;
  __syncthreads();
  if (ph == 0) {
    acc += part[0][q];
    acc += part[1][q];
    acc += part[2][q];
    uint2 o;
    o.x = pk2bf(acc[0], acc[1]);
    o.y = pk2bf(acc[2], acc[3]);
    *(uint2*)(dst + (size_t)b * 3072 + col) = o;
  }
}

// standalone make_q2 (fallback path only)
__global__ __launch_bounds__(256) void make_q2(
    ushort* __restrict__ q2b, const float* __restrict__ q2p, int ns,
    const float* __restrict__ h1, const float* __restrict__ eb)
{
  const int idx = blockIdx.x * 256 + threadIdx.x;
  const int b = idx >> 8;
  const int c4 = (idx & 255) * 4;
  const int oidx = b * 1024 + c4;
  f32x4 a = {0.f, 0.f, 0.f, 0.f};
  for (int s = 0; s < ns; s++)
    a += *(const f32x4*)(q2p + (size_t)s * 262144 + oidx);
  a += *(const f32x4*)(h1 + oidx);
  a += *(const f32x4*)(eb + c4);
  uint2 o;
  o.x = pk2bf(a[0], a[1]);
  o.y = pk2bf(a[2], a[3]);
  *(uint2*)(q2b + oidx) = o;
}

extern "C" void kernel_launch(void* const* d_in, const int* in_sizes, int n_in,
                              void* d_out, int out_size, void* d_ws, size_t ws_size,
                              hipStream_t stream)
{
  const float* xt        = (const float*)d_in[0];
  const float* fc        = (const float*)d_in[1];
  const float* att_feats = (const float*)d_in[2];
  const float* p_att     = (const float*)d_in[3];
  const float* st_h      = (const float*)d_in[4];
  const float* st_c      = (const float*)d_in[5];
  const float* wi[3] = {(const float*)d_in[6],  (const float*)d_in[10], (const float*)d_in[14]};
  const float* bi[3] = {(const float*)d_in[7],  (const float*)d_in[11], (const float*)d_in[15]};
  const float* wh[3] = {(const float*)d_in[8],  (const float*)d_in[12], (const float*)d_in[16]};
  const float* bh[3] = {(const float*)d_in[9],  (const float*)d_in[13], (const float*)d_in[17]};
  const float* a_hw[2] = {(const float*)d_in[18], (const float*)d_in[22]};
  const float* a_hb[2] = {(const float*)d_in[19], (const float*)d_in[23]};
  const float* a_aw[2] = {(const float*)d_in[20], (const float*)d_in[24]};
  const float* a_ab[2] = {(const float*)d_in[21], (const float*)d_in[25]};
  const float* emb2_w = (const float*)d_in[26];
  const float* emb2_b = (const float*)d_in[27];

  float* out    = (float*)d_out;
  float* out_h2 = out;
  float* out_h  = out + 262144;
  float* out_c  = out + 262144 + 786432;
  const int BR = B_ * R_;
  const int ns = 4;

  dim3 blk(256);
  auto jobL = [&](float* C, const ushort* Xb, const float* W1, const float* W2) {
    GJob j;
    j.C = C; j.ldc = 5120; j.pstride = (size_t)256 * 5120;
    j.Xb = Xb; j.ldx = 3072;
    j.W1 = W1; j.ldw1 = 2048; j.K1 = 2048;
    j.W2 = W2; j.ldw2 = 1024;
    j.K = 3072; j.nbn = 80; j.ns = ns;
    return j;
  };
  auto jobS = [&](float* C, int ldc, const ushort* Xb, int ldx,
                  const float* W, int ldw, int K, int N) {
    GJob j;
    j.C = C; j.ldc = ldc; j.pstride = (size_t)256 * ldc;
    j.Xb = Xb; j.ldx = ldx;
    j.W1 = W; j.ldw1 = ldw; j.K1 = K;
    j.W2 = W; j.ldw2 = ldw;
    j.K = K; j.nbn = N / 64; j.ns = ns;
    return j;
  };
  auto launch1 = [&](GJob j) {
    int total = j.nbn * 4 * j.ns;
    hipLaunchKernelGGL(gemm_k, dim3(total), blk, 0, stream, j, j, total);
  };
  auto launch2 = [&](GJob a, GJob b) {
    int ta = a.nbn * 4 * a.ns;
    int tb = b.nbn * 4 * b.ns;
    hipLaunchKernelGGL(gemm_k, dim3(ta + tb), blk, 0, stream, a, b, ta);
  };

  // ws layout: Sp(4) | Xb0..2 | attHp(4) | sc | qsum | q2p(4) | q2b
  const size_t NEED = 33230848u;
  float*  Sp    = (float*)d_ws;
  ushort* Xb0   = (ushort*)(Sp + (size_t)ns * 1310720);
  ushort* Xb1   = Xb0 + 786432;
  ushort* Xb2   = Xb1 + 786432;
  float*  attHp = (float*)(Xb2 + 786432);
  float*  sc    = attHp + (size_t)ns * 131072;
  float*  qsum  = sc + 50176;                     // 131072 f

  if (ws_size >= NEED) {
    float*  q2p = qsum + 131072;                  // 4 x 262144 f
    ushort* q2b = (ushort*)(q2p + (size_t)4 * 262144);

    pack5<<<1280, 256, 0, stream>>>(xt, Xb0, fc, Xb0 + 1024, st_h, Xb0 + 2048,
                                    st_h + BR, Xb1 + 2048,
                                    st_h + 2 * BR, Xb2 + 2048);

    // ---- LSTM 0
    launch1(jobL(Sp, Xb0, wi[0], wh[0]));
    lstm_gates<<<256, 256, 0, stream>>>(Sp, ns, bi[0], bh[0], st_c,
                                        out_h, out_c, Xb1, nullptr,
                                        nullptr, 0, nullptr, nullptr);

    // ---- Attention 1 (query = h0)
    launch1(jobS(attHp, 512, Xb1, 3072, a_hw[0], 1024, 1024, 512));
    att_prep<<<128, 256, 0, stream>>>(qsum, attHp, ns, a_hb[0]);
    att_scores<<<(B_ * L_) / 4, 256, 0, stream>>>(sc, p_att, qsum,
                                                  a_aw[0], a_ab[0]);
    att_smw<<<B_ * 4, 256, 0, stream>>>(Xb1 + 1024, sc, att_feats);

    // ---- LSTM1 GEMM || q2 GEMM
    launch2(jobL(Sp, Xb1, wi[1], wh[1]),
            jobS(q2p, 1024, Xb1 + 1024, 3072, emb2_w, 1024, 1024, 1024));
    lstm_gates<<<256, 256, 0, stream>>>(Sp, ns, bi[1], bh[1], st_c + BR,
                                        out_h + BR, out_c + BR, Xb2, nullptr,
                                        q2p, 4, emb2_b, q2b);

    // ---- Attention 2 (query = q2b)
    launch1(jobS(attHp, 512, q2b, 1024, a_hw[1], 1024, 1024, 512));
    att_prep<<<128, 256, 0, stream>>>(qsum, attHp, ns, a_hb[1]);
    att_scores<<<(B_ * L_) / 4, 256, 0, stream>>>(sc, p_att, qsum,
                                                  a_aw[1], a_ab[1]);
    att_smw<<<B_ * 4, 256, 0, stream>>>(Xb2 + 1024, sc, att_feats);

    // ---- LSTM 2
    launch1(jobL(Sp, Xb2, wi[2], wh[2]));
    lstm_gates<<<256, 256, 0, stream>>>(Sp, ns, bi[2], bh[2], st_c + 2 * BR,
                                        out_h + 2 * BR, out_c + 2 * BR,
                                        nullptr, out_h2,
                                        nullptr, 0, nullptr, nullptr);
    return;
  }

  // ================= fallback (q2p aliases Sp; standalone make_q2) =========
  float*  q2p = Sp;
  ushort* q2b = (ushort*)(Sp + (size_t)ns * 262144);

  pack5<<<1280, 256, 0, stream>>>(xt, Xb0, fc, Xb0 + 1024, st_h, Xb0 + 2048,
                                  st_h + BR, Xb1 + 2048,
                                  st_h + 2 * BR, Xb2 + 2048);
  launch1(jobL(Sp, Xb0, wi[0], wh[0]));
  lstm_gates<<<256, 256, 0, stream>>>(Sp, ns, bi[0], bh[0], st_c,
                                      out_h, out_c, Xb1, nullptr,
                                      nullptr, 0, nullptr, nullptr);
  launch1(jobS(attHp, 512, Xb1, 3072, a_hw[0], 1024, 1024, 512));
  att_prep<<<128, 256, 0, stream>>>(qsum, attHp, ns, a_hb[0]);
  att_scores<<<(B_ * L_) / 4, 256, 0, stream>>>(sc, p_att, qsum,
                                                a_aw[0], a_ab[0]);
  att_smw<<<B_ * 4, 256, 0, stream>>>(Xb1 + 1024, sc, att_feats);
  launch1(jobL(Sp, Xb1, wi[1], wh[1]));
  lstm_gates<<<256, 256, 0, stream>>>(Sp, ns, bi[1], bh[1], st_c + BR,
                                      out_h + BR, out_c + BR, Xb2, nullptr,
                                      nullptr, 0, nullptr, nullptr);
  launch1(jobS(q2p, 1024, Xb1 + 1024, 3072, emb2_w, 1024, 1024, 1024));
  make_q2<<<256, 256, 0, stream>>>(q2b, q2p, ns, out_h + BR, emb2_b);
  launch1(jobS(attHp, 512, q2b, 1024, a_hw[1], 1024, 1024, 512));
  att_prep<<<128, 256, 0, stream>>>(qsum, attHp, ns, a_hb[1]);
  att_scores<<<(B_ * L_) / 4, 256, 0, stream>>>(sc, p_att, qsum,
                                                a_aw[1], a_ab[1]);
  att_smw<<<B_ * 4, 256, 0, stream>>>(Xb2 + 1024, sc, att_feats);
  launch1(jobL(Sp, Xb2, wi[2], wh[2]));
  lstm_gates<<<256, 256, 0, stream>>>(Sp, ns, bi[2], bh[2], st_c + 2 * BR,
                                      out_h + 2 * BR, out_c + 2 * BR,
                                      nullptr, out_h2,
                                      nullptr, 0, nullptr, nullptr);
}